// Round 3
// baseline (911.679 us; speedup 1.0000x reference)
//
#include <hip/hip_runtime.h>
#include <stdint.h>
#include <stddef.h>

// SwinV2-B stage-3 window attention, MI355X bf16-MFMA pipeline.
// Round 3: 256x256/8-wave quadrant-phase GEMMs (raw barriers, late vmcnt, setprio).
// ws layout (requires ws_size >= ~409 MB):
//   [0)            QKV bf16 [131072][1536]  (q|k|v cols; attn overwrites q-cols with its output)
//   [402653184)    CMB  f32 [16w][16h][64][64]  combined 16*sigmoid(cpb)+mask
//   [406847488)    SIG  f32 [225][16]
//   [406861888)    WQB  bf16 [1536][512]   qkv_w
//   [408434752)    WPB  bf16 [512][512]    proj_w

typedef __attribute__((ext_vector_type(8))) short bf16x8;
typedef __attribute__((ext_vector_type(4))) float f32x4;
typedef __attribute__((ext_vector_type(4))) unsigned short us4;
typedef __attribute__((ext_vector_type(8))) unsigned short us8;
typedef unsigned short u16;
typedef unsigned int u32;

#define FENCE() asm volatile("" ::: "memory")
#define WAITV0() asm volatile("s_waitcnt vmcnt(0)" ::: "memory")
#define WAITL0() asm volatile("s_waitcnt lgkmcnt(0)" ::: "memory")

__device__ __forceinline__ u16 f2bf(float f) {
  union { __bf16 b; u16 u; } cv;
  cv.b = (__bf16)f;            // hardware RNE convert on gfx950
  return cv.u;
}
__device__ __forceinline__ float bf2f(u16 s) {
  return __uint_as_float(((u32)s) << 16);
}
__device__ __forceinline__ void gl_lds16(const void* g, void* l) {
  __builtin_amdgcn_global_load_lds(
      (const __attribute__((address_space(1))) u32*)g,
      (__attribute__((address_space(3))) u32*)l, 16, 0, 0);
}
__device__ __forceinline__ f32x4 mfma16(bf16x8 a, bf16x8 b, f32x4 c) {
  return __builtin_amdgcn_mfma_f32_16x16x32_bf16(a, b, c, 0, 0, 0);
}

// ---------------- prep kernels ----------------

__global__ void conv_w_kernel(const float* __restrict__ QW, const float* __restrict__ PW,
                              u16* __restrict__ WQB, u16* __restrict__ WPB) {
  int idx = blockIdx.x * 256 + threadIdx.x;   // 262144 float4 chunks total
  const int NQ = 1536 * 512 / 4;              // 196608
  float4 v; u16* dst;
  if (idx < NQ) { v = ((const float4*)QW)[idx]; dst = WQB + (size_t)idx * 4; }
  else { int k = idx - NQ; v = ((const float4*)PW)[k]; dst = WPB + (size_t)k * 4; }
  us4 u; u.x = f2bf(v.x); u.y = f2bf(v.y); u.z = f2bf(v.z); u.w = f2bf(v.w);
  *(us4*)dst = u;
}

__global__ void sig16_kernel(const float* __restrict__ CT, const float* __restrict__ W1,
                             const float* __restrict__ B1, const float* __restrict__ W2,
                             float* __restrict__ SIG) {
  int i = blockIdx.x;            // 0..224
  int tid = threadIdx.x;         // 256
  float c0 = CT[i * 2 + 0], c1 = CT[i * 2 + 1];
  float a[16];
  #pragma unroll
  for (int hh = 0; hh < 16; ++hh) a[hh] = 0.f;
  #pragma unroll
  for (int jj = 0; jj < 2; ++jj) {
    int j = tid + jj * 256;
    float h = fmaxf(c0 * W1[j * 2 + 0] + c1 * W1[j * 2 + 1] + B1[j], 0.f);
    #pragma unroll
    for (int hh = 0; hh < 16; ++hh) a[hh] += h * W2[hh * 512 + j];
  }
  __shared__ float red[4][16];
  #pragma unroll
  for (int hh = 0; hh < 16; ++hh) {
    float v = a[hh];
    for (int m = 1; m < 64; m <<= 1) v += __shfl_xor(v, m);
    if ((tid & 63) == 0) red[tid >> 6][hh] = v;
  }
  __syncthreads();
  if (tid < 16) {
    float v = red[0][tid] + red[1][tid] + red[2][tid] + red[3][tid];
    SIG[i * 16 + tid] = 16.f / (1.f + __expf(-v));
  }
}

__global__ void cmb_kernel(const float* __restrict__ SIG, const float* __restrict__ MASK,
                           const int* __restrict__ RPI, float* __restrict__ CMB) {
  int b = blockIdx.x;            // (w,h) = 256 blocks
  int w = b >> 4, h = b & 15;
  int tid = threadIdx.x;
  const float* mrow = &MASK[(size_t)w * 4096];
  float* crow = &CMB[(size_t)b * 4096];
  #pragma unroll
  for (int it = 0; it < 16; ++it) {
    int nm = it * 256 + tid;
    crow[nm] = SIG[RPI[nm] * 16 + h] + mrow[nm];
  }
}

// ---------------- qkv GEMM: [131072,512]f32 @ WQB^T -> bf16 [131072,1536] ----------------
// 256x256 tile, BK=64, 8 waves (2x4), dbuf LDS, 4 quadrant-phases/K-tile.
// A reg-staged (f32->bf16 cvt, swizzled ds_write at q3); B via gl_lds (source pre-swizzled).

__global__ __launch_bounds__(512, 1) void qkv_gemm(
    const float* __restrict__ X, const u16* __restrict__ WB,
    const float* __restrict__ QB, const float* __restrict__ VB,
    u16* __restrict__ QKV) {
  __shared__ u16 S[65536];  // [buf:2][ A[256][64] | B[256][64] ]  (131072 B)
  const int tid = threadIdx.x, lane = tid & 63, w = tid >> 6;
  int bid = blockIdx.x;                           // 3072 = 512m x 6n
  int swz = (bid & 7) * 384 + (bid >> 3);         // bijective XCD swizzle
  const int mt = swz / 6, nt = swz - mt * 6;
  const long m0 = (long)mt * 256, n0 = (long)nt * 256;
  const int wm = w >> 2, wn = w & 3;              // 2x4 waves; wave tile 128x64
  const int fr = lane & 15;
  const int fsw = ((lane >> 4) ^ (lane & 7)) << 3;  // u16 offset of swizzled ks=0 chunk
  const int akc = tid & 15, arow = tid >> 4;      // A stage: col-chunk, row-in-32
  const f32x4 zf = {0.f, 0.f, 0.f, 0.f};

  f32x4 acc[8][4];
  #pragma unroll
  for (int mi = 0; mi < 8; ++mi)
    #pragma unroll
    for (int ni = 0; ni < 4; ++ni) acc[mi][ni] = zf;

  float4 av[8];
  auto loadA = [&](int kt) {
    #pragma unroll
    for (int i = 0; i < 8; ++i)
      av[i] = *(const float4*)&X[(m0 + i * 32 + arow) * 512 + kt * 64 + akc * 4];
  };
  auto writeA = [&](int kt) {
    u16* dst = &S[(kt & 1) * 32768];
    #pragma unroll
    for (int i = 0; i < 8; ++i) {
      int row = i * 32 + arow;
      us4 u; u.x = f2bf(av[i].x); u.y = f2bf(av[i].y); u.z = f2bf(av[i].z); u.w = f2bf(av[i].w);
      *(us4*)&dst[row * 64 + (((akc >> 1) ^ (row & 7)) << 3) + ((akc & 1) << 2)] = u;
    }
  };
  auto stageB = [&](int kt, int p) {              // B half p: rows n0+p*128 .. +127
    u16* dst = &S[(kt & 1) * 32768 + 16384 + p * 8192];
    #pragma unroll
    for (int i = 0; i < 2; ++i) {
      int ch = i * 512 + w * 64 + lane;
      int row = ch >> 3, kcs = (ch & 7) ^ (row & 7);
      gl_lds16(&WB[(size_t)(n0 + p * 128 + row) * 512 + kt * 64 + kcs * 8],
               &dst[(i * 512 + w * 64) * 8]);
    }
  };

  // prologue: tile 0
  loadA(0); stageB(0, 0); stageB(0, 1);
  WAITV0(); writeA(0); WAITL0();
  FENCE(); __builtin_amdgcn_s_barrier(); FENCE();

  for (int t = 0; t < 8; ++t) {
    const u16* As_ = &S[(t & 1) * 32768];
    const u16* Bs_ = As_ + 16384;
    #pragma unroll
    for (int q = 0; q < 4; ++q) {
      const int qm = q >> 1, qn = q & 1;
      bf16x8 af0[4], af1[4], bv0[2], bv1[2];
      #pragma unroll
      for (int m = 0; m < 4; ++m) {
        const u16* p = As_ + (wm * 128 + (qm * 4 + m) * 16 + fr) * 64 + fsw;
        af0[m] = *(const bf16x8*)p;
        af1[m] = *(const bf16x8*)((const u16*)((uintptr_t)p ^ 64));
      }
      #pragma unroll
      for (int n = 0; n < 2; ++n) {
        const u16* p = Bs_ + (wn * 64 + (qn * 2 + n) * 16 + fr) * 64 + fsw;
        bv0[n] = *(const bf16x8*)p;
        bv1[n] = *(const bf16x8*)((const u16*)((uintptr_t)p ^ 64));
      }
      if (t < 7) {                                 // stage tile t+1 (other buffer)
        if (q == 0) loadA(t + 1);
        else if (q == 1) stageB(t + 1, 0);
        else if (q == 2) stageB(t + 1, 1);
      }
      FENCE(); __builtin_amdgcn_s_barrier(); FENCE();
      __builtin_amdgcn_s_setprio(1);
      #pragma unroll
      for (int m = 0; m < 4; ++m)
        #pragma unroll
        for (int n = 0; n < 2; ++n) {
          acc[qm * 4 + m][qn * 2 + n] = mfma16(af0[m], bv0[n], acc[qm * 4 + m][qn * 2 + n]);
          acc[qm * 4 + m][qn * 2 + n] = mfma16(af1[m], bv1[n], acc[qm * 4 + m][qn * 2 + n]);
        }
      __builtin_amdgcn_s_setprio(0);
      if (q == 3 && t < 7) { WAITV0(); writeA(t + 1); WAITL0(); }
      FENCE(); __builtin_amdgcn_s_barrier(); FENCE();
    }
  }

  #pragma unroll
  for (int ni = 0; ni < 4; ++ni) {
    const long c = n0 + wn * 64 + ni * 16 + fr;
    float bias = (c < 512) ? QB[c] : (c < 1024 ? 0.f : VB[c - 1024]);
    #pragma unroll
    for (int mi = 0; mi < 8; ++mi)
      #pragma unroll
      for (int r = 0; r < 4; ++r) {
        long row = m0 + wm * 128 + mi * 16 + (lane >> 4) * 4 + r;
        QKV[row * 1536 + c] = f2bf(acc[mi][ni][r] + bias);
      }
  }
}

// ---------------- attention: 1 block per window, 4 waves coop per head ----------------

__global__ __launch_bounds__(256, 4) void attn_kernel(
    u16* __restrict__ QKV, const float* __restrict__ CMB, const float* __restrict__ LS) {
  __shared__ u16 sm[7424];       // 14848 B
  u16* qs = sm;                  // [64][40] (aliased by ps)
  u16* ksm = sm + 2560;          // [64][40] (aliased by ps)
  u16* ps = sm;                  // [64][72]
  u16* vt = sm + 5120;           // [32][72] (v transposed: [d][k])
  const int tid = threadIdx.x, lane = tid & 63, w = tid >> 6;
  const int b = blockIdx.x, wi = b & 15;
  const size_t base = (size_t)b * 64 * 1536;
  const int cl = lane & 15, lg = lane >> 4;
  const int srow = tid >> 2, sck = tid & 3;       // q/k staging: 4 threads per row
  const int vd = tid & 31, vkb = tid >> 5;        // v transpose staging
  const f32x4 zf = {0.f, 0.f, 0.f, 0.f};

  for (int h = 0; h < 16; ++h) {
    const float scale = __expf(fminf(LS[h], 4.6051702f));   // min(log s, log 100)
    { // q: load row, normalize (f32), *scale, -> LDS bf16
      us8 qv = *(const us8*)&QKV[base + (size_t)srow * 1536 + h * 32 + sck * 8];
      float qf[8]; float ss = 0.f;
      #pragma unroll
      for (int j = 0; j < 8; ++j) { qf[j] = bf2f(qv[j]); ss += qf[j] * qf[j]; }
      ss += __shfl_xor(ss, 1); ss += __shfl_xor(ss, 2);
      float rn = scale / fmaxf(sqrtf(ss), 1e-12f);
      us8 qo;
      #pragma unroll
      for (int j = 0; j < 8; ++j) qo[j] = f2bf(qf[j] * rn);
      *(us8*)&qs[srow * 40 + sck * 8] = qo;
    }
    { // k: normalize
      us8 kv = *(const us8*)&QKV[base + (size_t)srow * 1536 + 512 + h * 32 + sck * 8];
      float kf[8]; float ss = 0.f;
      #pragma unroll
      for (int j = 0; j < 8; ++j) { kf[j] = bf2f(kv[j]); ss += kf[j] * kf[j]; }
      ss += __shfl_xor(ss, 1); ss += __shfl_xor(ss, 2);
      float rn = 1.f / fmaxf(sqrtf(ss), 1e-12f);
      us8 ko;
      #pragma unroll
      for (int j = 0; j < 8; ++j) ko[j] = f2bf(kf[j] * rn);
      *(us8*)&ksm[srow * 40 + sck * 8] = ko;
    }
    { // v: gather column vd (8 k's), write transposed row
      us8 vo;
      #pragma unroll
      for (int e = 0; e < 8; ++e)
        vo[e] = QKV[base + (size_t)(vkb * 8 + e) * 1536 + 1024 + h * 32 + vd];
      *(us8*)&vt[vd * 72 + vkb * 8] = vo;
    }
    __syncthreads();

    // QK^T: wave w owns rows [16w,16w+16)
    bf16x8 aq = *(const bf16x8*)&qs[(w * 16 + cl) * 40 + lg * 8];
    f32x4 s4[4];
    #pragma unroll
    for (int nt = 0; nt < 4; ++nt) {
      bf16x8 bk = *(const bf16x8*)&ksm[(nt * 16 + cl) * 40 + lg * 8];
      s4[nt] = mfma16(aq, bk, zf);
    }

    // + combined bias/mask, softmax in registers
    const float* cp = &CMB[((size_t)(wi * 16 + h)) << 12];
    const int r0 = w * 16 + lg * 4;
    float p[4][4];
    #pragma unroll
    for (int r = 0; r < 4; ++r) {
      float mx = -3.0e38f;
      #pragma unroll
      for (int q4 = 0; q4 < 4; ++q4) {
        float v = s4[q4][r] + cp[(r0 + r) * 64 + q4 * 16 + cl];
        p[q4][r] = v; mx = fmaxf(mx, v);
      }
      mx = fmaxf(mx, __shfl_xor(mx, 1));
      mx = fmaxf(mx, __shfl_xor(mx, 2));
      mx = fmaxf(mx, __shfl_xor(mx, 4));
      mx = fmaxf(mx, __shfl_xor(mx, 8));
      float sum = 0.f;
      #pragma unroll
      for (int q4 = 0; q4 < 4; ++q4) { float e = __expf(p[q4][r] - mx); p[q4][r] = e; sum += e; }
      sum += __shfl_xor(sum, 1); sum += __shfl_xor(sum, 2);
      sum += __shfl_xor(sum, 4); sum += __shfl_xor(sum, 8);
      float inv = 1.f / sum;
      #pragma unroll
      for (int q4 = 0; q4 < 4; ++q4) p[q4][r] *= inv;
    }
    __syncthreads();   // all waves done reading qs/ks before ps overwrite

    #pragma unroll
    for (int r = 0; r < 4; ++r)
      #pragma unroll
      for (int q4 = 0; q4 < 4; ++q4)
        ps[(r0 + r) * 72 + q4 * 16 + cl] = f2bf(p[q4][r]);

    // PV: out[64x32]; reads own-wave ps rows + shared vt
    f32x4 o4[2]; o4[0] = zf; o4[1] = zf;
    #pragma unroll
    for (int ks = 0; ks < 2; ++ks) {
      bf16x8 ap = *(const bf16x8*)&ps[(w * 16 + cl) * 72 + ks * 32 + lg * 8];
      #pragma unroll
      for (int n2 = 0; n2 < 2; ++n2) {
        bf16x8 bv = *(const bf16x8*)&vt[(n2 * 16 + cl) * 72 + ks * 32 + lg * 8];
        o4[n2] = mfma16(ap, bv, o4[n2]);
      }
    }
    // store attn-out over the q-region (cols h*32..h*32+31) of this window's rows
    #pragma unroll
    for (int n2 = 0; n2 < 2; ++n2)
      #pragma unroll
      for (int r = 0; r < 4; ++r)
        QKV[base + (size_t)(w * 16 + lg * 4 + r) * 1536 + h * 32 + n2 * 16 + cl] = f2bf(o4[n2][r]);
    __syncthreads();   // before next head's staging overwrites LDS
  }
}

// ---------------- proj GEMM: bf16 [131072,512](lda=1536) @ WPB^T + b -> f32 out ----------------
// Same 256x256 quadrant-phase template; both operands gl_lds (sources pre-swizzled).

__global__ __launch_bounds__(512, 1) void proj_gemm(
    const u16* __restrict__ A, const u16* __restrict__ WB,
    const float* __restrict__ PB, float* __restrict__ OUT) {
  __shared__ u16 S[65536];
  const int tid = threadIdx.x, lane = tid & 63, w = tid >> 6;
  int bid = blockIdx.x;                           // 1024 = 512m x 2n
  int swz = (bid & 7) * 128 + (bid >> 3);
  const int mt = swz >> 1, nt = swz & 1;
  const long m0 = (long)mt * 256, n0 = (long)nt * 256;
  const int wm = w >> 2, wn = w & 3;
  const int fr = lane & 15;
  const int fsw = ((lane >> 4) ^ (lane & 7)) << 3;
  const f32x4 zf = {0.f, 0.f, 0.f, 0.f};

  f32x4 acc[8][4];
  #pragma unroll
  for (int mi = 0; mi < 8; ++mi)
    #pragma unroll
    for (int ni = 0; ni < 4; ++ni) acc[mi][ni] = zf;

  auto stageA = [&](int kt, int p) {              // A half p from QKV q-region, lda 1536
    u16* dst = &S[(kt & 1) * 32768 + p * 8192];
    #pragma unroll
    for (int i = 0; i < 2; ++i) {
      int ch = i * 512 + w * 64 + lane;
      int row = ch >> 3, kcs = (ch & 7) ^ (row & 7);
      gl_lds16(&A[(size_t)(m0 + p * 128 + row) * 1536 + kt * 64 + kcs * 8],
               &dst[(i * 512 + w * 64) * 8]);
    }
  };
  auto stageB = [&](int kt, int p) {
    u16* dst = &S[(kt & 1) * 32768 + 16384 + p * 8192];
    #pragma unroll
    for (int i = 0; i < 2; ++i) {
      int ch = i * 512 + w * 64 + lane;
      int row = ch >> 3, kcs = (ch & 7) ^ (row & 7);
      gl_lds16(&WB[(size_t)(n0 + p * 128 + row) * 512 + kt * 64 + kcs * 8],
               &dst[(i * 512 + w * 64) * 8]);
    }
  };

  stageA(0, 0); stageA(0, 1); stageB(0, 0); stageB(0, 1);
  WAITV0();
  FENCE(); __builtin_amdgcn_s_barrier(); FENCE();

  for (int t = 0; t < 8; ++t) {
    const u16* As_ = &S[(t & 1) * 32768];
    const u16* Bs_ = As_ + 16384;
    #pragma unroll
    for (int q = 0; q < 4; ++q) {
      const int qm = q >> 1, qn = q & 1;
      bf16x8 af0[4], af1[4], bv0[2], bv1[2];
      #pragma unroll
      for (int m = 0; m < 4; ++m) {
        const u16* p = As_ + (wm * 128 + (qm * 4 + m) * 16 + fr) * 64 + fsw;
        af0[m] = *(const bf16x8*)p;
        af1[m] = *(const bf16x8*)((const u16*)((uintptr_t)p ^ 64));
      }
      #pragma unroll
      for (int n = 0; n < 2; ++n) {
        const u16* p = Bs_ + (wn * 64 + (qn * 2 + n) * 16 + fr) * 64 + fsw;
        bv0[n] = *(const bf16x8*)p;
        bv1[n] = *(const bf16x8*)((const u16*)((uintptr_t)p ^ 64));
      }
      if (t < 7) {                                // A first (colder), B (L2-hot) last
        if (q == 0) stageA(t + 1, 0);
        else if (q == 1) stageA(t + 1, 1);
        else if (q == 2) stageB(t + 1, 0);
        else stageB(t + 1, 1);
      }
      FENCE(); __builtin_amdgcn_s_barrier(); FENCE();
      __builtin_amdgcn_s_setprio(1);
      #pragma unroll
      for (int m = 0; m < 4; ++m)
        #pragma unroll
        for (int n = 0; n < 2; ++n) {
          acc[qm * 4 + m][qn * 2 + n] = mfma16(af0[m], bv0[n], acc[qm * 4 + m][qn * 2 + n]);
          acc[qm * 4 + m][qn * 2 + n] = mfma16(af1[m], bv1[n], acc[qm * 4 + m][qn * 2 + n]);
        }
      __builtin_amdgcn_s_setprio(0);
      if (q == 3 && t < 7) { WAITV0(); }
      FENCE(); __builtin_amdgcn_s_barrier(); FENCE();
    }
  }

  #pragma unroll
  for (int ni = 0; ni < 4; ++ni) {
    const long c = n0 + wn * 64 + ni * 16 + fr;
    float bias = PB[c];
    #pragma unroll
    for (int mi = 0; mi < 8; ++mi)
      #pragma unroll
      for (int r = 0; r < 4; ++r) {
        long row = m0 + wm * 128 + mi * 16 + (lane >> 4) * 4 + r;
        OUT[row * 512 + c] = acc[mi][ni][r] + bias;
      }
  }
}

// ---------------- launch ----------------

extern "C" void kernel_launch(void* const* d_in, const int* in_sizes, int n_in,
                              void* d_out, int out_size, void* d_ws, size_t ws_size,
                              hipStream_t stream) {
  const float* X    = (const float*)d_in[0];
  const float* MASK = (const float*)d_in[1];
  const float* QW   = (const float*)d_in[2];
  const float* QB   = (const float*)d_in[3];
  const float* VB   = (const float*)d_in[4];
  const float* LS   = (const float*)d_in[5];
  const float* CW1  = (const float*)d_in[6];
  const float* CB1  = (const float*)d_in[7];
  const float* CW2  = (const float*)d_in[8];
  const float* PW   = (const float*)d_in[9];
  const float* PB   = (const float*)d_in[10];
  const float* CT   = (const float*)d_in[11];
  const int*   RPI  = (const int*)d_in[12];
  float* OUT = (float*)d_out;

  char* ws = (char*)d_ws;
  u16*   QKV = (u16*)ws;                          // 402,653,184 B
  float* CMB = (float*)(ws + 402653184ull);       //   4,194,304 B
  float* SIG = (float*)(ws + 406847488ull);       //      14,400 B
  u16*   WQB = (u16*)(ws + 406861888ull);         //   1,572,864 B
  u16*   WPB = (u16*)(ws + 408434752ull);         //     524,288 B (end ~409 MB)

  conv_w_kernel<<<1024, 256, 0, stream>>>(QW, PW, WQB, WPB);
  sig16_kernel<<<225, 256, 0, stream>>>(CT, CW1, CB1, CW2, SIG);
  cmb_kernel<<<256, 256, 0, stream>>>(SIG, MASK, RPI, CMB);
  qkv_gemm<<<3072, 512, 0, stream>>>(X, WQB, QB, VB, QKV);
  attn_kernel<<<2048, 256, 0, stream>>>(QKV, CMB, LS);
  proj_gemm<<<1024, 512, 0, stream>>>(QKV, WPB, PB, OUT);
}

// Round 4
// 824.121 us; speedup vs baseline: 1.1062x; 1.1062x over previous
//
#include <hip/hip_runtime.h>
#include <stdint.h>
#include <stddef.h>

// SwinV2-B stage-3 window attention, MI355X bf16-MFMA pipeline.
// Round 4: qkv = 256x256 8-wave quadrant pipeline with counted vmcnt(4)
// (true T3+T4), fed by a bf16 pre-convert of X. proj/attn = round-2 forms.
// Big ws layout (ws_size >= 543,178,752 B):
//   [0)            QKV bf16 [131072][1536]
//   [402653184)    XB  bf16 [131072][512]
//   [536870912)    CMB f32 [16w][16h][64][64]
//   [541065216)    SIG f32 [225][16] (pad 16K)
//   [541081600)    WQB bf16 [1536][512]
//   [542654464)    WPB bf16 [512][512]
// Fallback (small ws): round-2 layout, reg-staged qkv.

typedef __attribute__((ext_vector_type(8))) short bf16x8;
typedef __attribute__((ext_vector_type(4))) float f32x4;
typedef __attribute__((ext_vector_type(4))) unsigned short us4;
typedef __attribute__((ext_vector_type(8))) unsigned short us8;
typedef unsigned short u16;
typedef unsigned int u32;

#define FENCE() asm volatile("" ::: "memory")
#define WAITV4() asm volatile("s_waitcnt vmcnt(4)" ::: "memory")
#define WAITV0() asm volatile("s_waitcnt vmcnt(0)" ::: "memory")
#define WAITL0() asm volatile("s_waitcnt lgkmcnt(0)" ::: "memory")

__device__ __forceinline__ u16 f2bf(float f) {
  union { __bf16 b; u16 u; } cv;
  cv.b = (__bf16)f;            // hardware RNE convert on gfx950
  return cv.u;
}
__device__ __forceinline__ float bf2f(u16 s) {
  return __uint_as_float(((u32)s) << 16);
}
__device__ __forceinline__ void gl_lds16(const void* g, void* l) {
  __builtin_amdgcn_global_load_lds(
      (const __attribute__((address_space(1))) u32*)g,
      (__attribute__((address_space(3))) u32*)l, 16, 0, 0);
}
__device__ __forceinline__ f32x4 mfma16(bf16x8 a, bf16x8 b, f32x4 c) {
  return __builtin_amdgcn_mfma_f32_16x16x32_bf16(a, b, c, 0, 0, 0);
}
__device__ __forceinline__ bf16x8 ldswz(const u16* p, int ks) {
  return *(const bf16x8*)((const u16*)((uintptr_t)p ^ (uintptr_t)(ks << 6)));
}

// ---------------- prep kernels ----------------

__global__ void conv_w_kernel(const float* __restrict__ QW, const float* __restrict__ PW,
                              u16* __restrict__ WQB, u16* __restrict__ WPB) {
  int idx = blockIdx.x * 256 + threadIdx.x;   // 262144 float4 chunks total
  const int NQ = 1536 * 512 / 4;              // 196608
  float4 v; u16* dst;
  if (idx < NQ) { v = ((const float4*)QW)[idx]; dst = WQB + (size_t)idx * 4; }
  else { int k = idx - NQ; v = ((const float4*)PW)[k]; dst = WPB + (size_t)k * 4; }
  us4 u; u.x = f2bf(v.x); u.y = f2bf(v.y); u.z = f2bf(v.z); u.w = f2bf(v.w);
  *(us4*)dst = u;
}

__global__ void xconv_kernel(const float* __restrict__ X, u16* __restrict__ XB) {
  size_t idx = (size_t)blockIdx.x * 256 + threadIdx.x;   // 8,388,608 threads, 8 f32 each
  float4 a = ((const float4*)X)[idx * 2];
  float4 b = ((const float4*)X)[idx * 2 + 1];
  us8 o;
  o[0] = f2bf(a.x); o[1] = f2bf(a.y); o[2] = f2bf(a.z); o[3] = f2bf(a.w);
  o[4] = f2bf(b.x); o[5] = f2bf(b.y); o[6] = f2bf(b.z); o[7] = f2bf(b.w);
  *(us8*)&XB[idx * 8] = o;
}

__global__ void sig16_kernel(const float* __restrict__ CT, const float* __restrict__ W1,
                             const float* __restrict__ B1, const float* __restrict__ W2,
                             float* __restrict__ SIG) {
  int i = blockIdx.x;            // 0..224
  int tid = threadIdx.x;         // 256
  float c0 = CT[i * 2 + 0], c1 = CT[i * 2 + 1];
  float a[16];
  #pragma unroll
  for (int hh = 0; hh < 16; ++hh) a[hh] = 0.f;
  #pragma unroll
  for (int jj = 0; jj < 2; ++jj) {
    int j = tid + jj * 256;
    float h = fmaxf(c0 * W1[j * 2 + 0] + c1 * W1[j * 2 + 1] + B1[j], 0.f);
    #pragma unroll
    for (int hh = 0; hh < 16; ++hh) a[hh] += h * W2[hh * 512 + j];
  }
  __shared__ float red[4][16];
  #pragma unroll
  for (int hh = 0; hh < 16; ++hh) {
    float v = a[hh];
    for (int m = 1; m < 64; m <<= 1) v += __shfl_xor(v, m);
    if ((tid & 63) == 0) red[tid >> 6][hh] = v;
  }
  __syncthreads();
  if (tid < 16) {
    float v = red[0][tid] + red[1][tid] + red[2][tid] + red[3][tid];
    SIG[i * 16 + tid] = 16.f / (1.f + __expf(-v));
  }
}

__global__ void cmb_kernel(const float* __restrict__ SIG, const float* __restrict__ MASK,
                           const int* __restrict__ RPI, float* __restrict__ CMB) {
  int b = blockIdx.x;            // (w,h) = 256 blocks
  int w = b >> 4, h = b & 15;
  int tid = threadIdx.x;
  const float* mrow = &MASK[(size_t)w * 4096];
  float* crow = &CMB[(size_t)b * 4096];
  #pragma unroll
  for (int it = 0; it < 16; ++it) {
    int nm = it * 256 + tid;
    crow[nm] = SIG[RPI[nm] * 16 + h] + mrow[nm];
  }
}

// ---------------- qkv GEMM (8-phase): XB bf16 [131072,512] @ WQB^T -> bf16 [131072,1536] ----
// 256x256 tile, BK=64, 8 waves (2Mx4N), dbuf LDS 128KB, counted vmcnt(4) once per K-tile.
// Reads: p0{A0,B0} p1{A0,B1} p2{A1,B0} p3{A1,B1}; stages: p0->B1(t+1), p1->A1(t+1),
// p2->A0(t+2), p3->B0(t+2)+vmcnt(4). Next tile's 4 halves proven resident at each boundary.

__global__ __launch_bounds__(512, 1) void qkv_gemm8(
    const u16* __restrict__ XB, const u16* __restrict__ WB,
    const float* __restrict__ QB, const float* __restrict__ VB,
    u16* __restrict__ QKV) {
  __shared__ u16 S[65536];  // [buf:2][ A[256][64] | B[256][64] ]  131072 B
  const int tid = threadIdx.x, lane = tid & 63, w = tid >> 6;
  int bid = blockIdx.x;                           // 3072 = 512m x 6n
  int swz = (bid & 7) * 384 + (bid >> 3);         // bijective XCD swizzle
  const int mt = swz / 6, nt = swz - mt * 6;
  const long m0 = (long)mt * 256, n0 = (long)nt * 256;
  const int wm = w >> 2, wn = w & 3;              // quadrant-interleaved wave tiles
  const int fr = lane & 15, lg = lane >> 4;
  const int fsw = (lg ^ (lane & 7)) << 3;         // swizzled ks=0 chunk (u16 units)
  const f32x4 zf = {0.f, 0.f, 0.f, 0.f};

  f32x4 acc[8][4];
  #pragma unroll
  for (int mi = 0; mi < 8; ++mi)
    #pragma unroll
    for (int ni = 0; ni < 4; ++ni) acc[mi][ni] = zf;

  auto stageA = [&](int kt, int h) {              // A half h: rows m0+h*128..+127
    int dst = (kt & 1) * 32768 + h * 8192;
    #pragma unroll
    for (int i = 0; i < 2; ++i) {
      int ch = i * 512 + tid;
      int row = ch >> 3, kcs = (ch & 7) ^ (row & 7);
      gl_lds16(&XB[(size_t)(m0 + h * 128 + row) * 512 + kt * 64 + kcs * 8],
               &S[dst + (i * 512 + w * 64) * 8]);
    }
  };
  auto stageB = [&](int kt, int h) {
    int dst = (kt & 1) * 32768 + 16384 + h * 8192;
    #pragma unroll
    for (int i = 0; i < 2; ++i) {
      int ch = i * 512 + tid;
      int row = ch >> 3, kcs = (ch & 7) ^ (row & 7);
      gl_lds16(&WB[(size_t)(n0 + h * 128 + row) * 512 + kt * 64 + kcs * 8],
               &S[dst + (i * 512 + w * 64) * 8]);
    }
  };

  // prologue: tile0 all 4 halves (oldest), then A0,B0 of tile1
  stageA(0, 0); stageB(0, 0); stageB(0, 1); stageA(0, 1);
  stageA(1, 0); stageB(1, 0);
  WAITV4();                                       // tile0 resident; A0(1),B0(1) in flight
  FENCE(); __builtin_amdgcn_s_barrier(); FENCE();

  for (int t = 0; t < 8; ++t) {
    const int buf = (t & 1) * 32768;
    #pragma unroll
    for (int p = 0; p < 4; ++p) {
      const int qm = p >> 1, qn = p & 1;
      bf16x8 af0[4], af1[4], bv0[2], bv1[2];
      #pragma unroll
      for (int m = 0; m < 4; ++m) {
        const u16* pA = &S[buf + (qm * 128 + wm * 64 + m * 16 + fr) * 64 + fsw];
        af0[m] = ldswz(pA, 0);
        af1[m] = ldswz(pA, 1);
      }
      #pragma unroll
      for (int n = 0; n < 2; ++n) {
        const u16* pB = &S[buf + 16384 + (qn * 128 + wn * 32 + n * 16 + fr) * 64 + fsw];
        bv0[n] = ldswz(pB, 0);
        bv1[n] = ldswz(pB, 1);
      }
      if (p == 0)      { if (t < 7) stageB(t + 1, 1); }
      else if (p == 1) { if (t < 7) stageA(t + 1, 1); }
      else if (p == 2) { if (t < 6) stageA(t + 2, 0); }
      else {
        if (t < 6) { stageB(t + 2, 0); WAITV4(); }
        else if (t == 6) { WAITV0(); }
      }
      FENCE(); __builtin_amdgcn_s_barrier(); FENCE();
      WAITL0(); __builtin_amdgcn_sched_barrier(0);
      __builtin_amdgcn_s_setprio(1);
      #pragma unroll
      for (int m = 0; m < 4; ++m)
        #pragma unroll
        for (int n = 0; n < 2; ++n) {
          acc[qm * 4 + m][qn * 2 + n] = mfma16(af0[m], bv0[n], acc[qm * 4 + m][qn * 2 + n]);
          acc[qm * 4 + m][qn * 2 + n] = mfma16(af1[m], bv1[n], acc[qm * 4 + m][qn * 2 + n]);
        }
      __builtin_amdgcn_s_setprio(0);
      FENCE(); __builtin_amdgcn_s_barrier(); FENCE();
    }
  }

  #pragma unroll
  for (int ni = 0; ni < 4; ++ni) {
    const long c = n0 + (ni >> 1) * 128 + wn * 32 + (ni & 1) * 16 + fr;
    float bias = (c < 512) ? QB[c] : (c < 1024 ? 0.f : VB[c - 1024]);
    #pragma unroll
    for (int mi = 0; mi < 8; ++mi)
      #pragma unroll
      for (int r = 0; r < 4; ++r) {
        long row = m0 + (mi >> 2) * 128 + wm * 64 + (mi & 3) * 16 + lg * 4 + r;
        QKV[row * 1536 + c] = f2bf(acc[mi][ni][r] + bias);
      }
  }
}

// ---------------- qkv GEMM fallback (round-2): reg-staged A, 128x128 ----------------

__global__ __launch_bounds__(256, 2) void qkv_gemm_rs(
    const float* __restrict__ X, const u16* __restrict__ WB,
    const float* __restrict__ QB, const float* __restrict__ VB,
    u16* __restrict__ QKV) {
  __shared__ u16 As[128 * 64];
  __shared__ u16 Bs[128 * 64];
  const int tid = threadIdx.x, lane = tid & 63, w = tid >> 6;
  int bid = blockIdx.x;
  int swz = (bid & 7) * 1536 + (bid >> 3);
  const int mt = swz / 12, nt = swz - mt * 12;
  const long m0 = (long)mt * 128, n0 = (long)nt * 128;
  const int wm = w >> 1, wn = w & 1;
  const f32x4 zf = {0.f, 0.f, 0.f, 0.f};

  f32x4 acc[4][4];
  #pragma unroll
  for (int mi = 0; mi < 4; ++mi)
    #pragma unroll
    for (int ni = 0; ni < 4; ++ni) acc[mi][ni] = zf;

  const int fr = lane & 15;
  const int fsw = ((lane >> 4) ^ (lane & 7)) * 8;
  const u16* Ap = &As[(wm * 64 + fr) * 64 + fsw];
  const u16* Bp = &Bs[(wn * 64 + fr) * 64 + fsw];

  for (int t = 0; t < 8; ++t) {
    float4 av[8];
    #pragma unroll
    for (int i = 0; i < 8; ++i) {
      int ch = tid + (i << 8);
      int row = ch >> 4, kc = ch & 15;
      av[i] = *(const float4*)&X[(m0 + row) * 512 + t * 64 + kc * 4];
    }
    #pragma unroll
    for (int i = 0; i < 4; ++i) {
      int ch = ((w << 2) + i) * 64 + lane;
      int row = ch >> 3, kc = (ch & 7) ^ (row & 7);
      gl_lds16(&WB[(n0 + row) * 512 + t * 64 + kc * 8], &Bs[((w << 2) + i) * 512]);
    }
    #pragma unroll
    for (int i = 0; i < 8; ++i) {
      int ch = tid + (i << 8);
      int row = ch >> 4, kc = ch & 15;
      int kcs = kc ^ ((row & 7) << 1);
      us4 u; u.x = f2bf(av[i].x); u.y = f2bf(av[i].y); u.z = f2bf(av[i].z); u.w = f2bf(av[i].w);
      *(us4*)&As[row * 64 + kcs * 4] = u;
    }
    __syncthreads();
    #pragma unroll
    for (int ks = 0; ks < 2; ++ks) {
      bf16x8 af[4], bfr[4];
      #pragma unroll
      for (int mi = 0; mi < 4; ++mi) af[mi] = ldswz(Ap + mi * 1024, ks);
      #pragma unroll
      for (int ni = 0; ni < 4; ++ni) bfr[ni] = ldswz(Bp + ni * 1024, ks);
      #pragma unroll
      for (int mi = 0; mi < 4; ++mi)
        #pragma unroll
        for (int ni = 0; ni < 4; ++ni)
          acc[mi][ni] = mfma16(af[mi], bfr[ni], acc[mi][ni]);
    }
    __syncthreads();
  }

  #pragma unroll
  for (int ni = 0; ni < 4; ++ni) {
    const long c = n0 + wn * 64 + ni * 16 + (lane & 15);
    float bias = (c < 512) ? QB[c] : (c < 1024 ? 0.f : VB[c - 1024]);
    #pragma unroll
    for (int mi = 0; mi < 4; ++mi)
      #pragma unroll
      for (int r = 0; r < 4; ++r) {
        long row = m0 + wm * 64 + mi * 16 + (lane >> 4) * 4 + r;
        QKV[row * 1536 + c] = f2bf(acc[mi][ni][r] + bias);
      }
  }
}

// ---------------- attention: 1 block per window, 4 waves coop per head ----------------

__global__ __launch_bounds__(256, 4) void attn_kernel(
    u16* __restrict__ QKV, const float* __restrict__ CMB, const float* __restrict__ LS) {
  __shared__ u16 sm[7424];       // 14848 B
  u16* qs = sm;                  // [64][40] (aliased by ps)
  u16* ksm = sm + 2560;          // [64][40] (aliased by ps)
  u16* ps = sm;                  // [64][72]
  u16* vt = sm + 5120;           // [32][72] (v transposed: [d][k])
  const int tid = threadIdx.x, lane = tid & 63, w = tid >> 6;
  const int b = blockIdx.x, wi = b & 15;
  const size_t base = (size_t)b * 64 * 1536;
  const int cl = lane & 15, lg = lane >> 4;
  const int srow = tid >> 2, sck = tid & 3;
  const int vd = tid & 31, vkb = tid >> 5;
  const f32x4 zf = {0.f, 0.f, 0.f, 0.f};

  for (int h = 0; h < 16; ++h) {
    const float scale = __expf(fminf(LS[h], 4.6051702f));
    {
      us8 qv = *(const us8*)&QKV[base + (size_t)srow * 1536 + h * 32 + sck * 8];
      float qf[8]; float ss = 0.f;
      #pragma unroll
      for (int j = 0; j < 8; ++j) { qf[j] = bf2f(qv[j]); ss += qf[j] * qf[j]; }
      ss += __shfl_xor(ss, 1); ss += __shfl_xor(ss, 2);
      float rn = scale / fmaxf(sqrtf(ss), 1e-12f);
      us8 qo;
      #pragma unroll
      for (int j = 0; j < 8; ++j) qo[j] = f2bf(qf[j] * rn);
      *(us8*)&qs[srow * 40 + sck * 8] = qo;
    }
    {
      us8 kv = *(const us8*)&QKV[base + (size_t)srow * 1536 + 512 + h * 32 + sck * 8];
      float kf[8]; float ss = 0.f;
      #pragma unroll
      for (int j = 0; j < 8; ++j) { kf[j] = bf2f(kv[j]); ss += kf[j] * kf[j]; }
      ss += __shfl_xor(ss, 1); ss += __shfl_xor(ss, 2);
      float rn = 1.f / fmaxf(sqrtf(ss), 1e-12f);
      us8 ko;
      #pragma unroll
      for (int j = 0; j < 8; ++j) ko[j] = f2bf(kf[j] * rn);
      *(us8*)&ksm[srow * 40 + sck * 8] = ko;
    }
    {
      us8 vo;
      #pragma unroll
      for (int e = 0; e < 8; ++e)
        vo[e] = QKV[base + (size_t)(vkb * 8 + e) * 1536 + 1024 + h * 32 + vd];
      *(us8*)&vt[vd * 72 + vkb * 8] = vo;
    }
    __syncthreads();

    bf16x8 aq = *(const bf16x8*)&qs[(w * 16 + cl) * 40 + lg * 8];
    f32x4 s4[4];
    #pragma unroll
    for (int nt = 0; nt < 4; ++nt) {
      bf16x8 bk = *(const bf16x8*)&ksm[(nt * 16 + cl) * 40 + lg * 8];
      s4[nt] = mfma16(aq, bk, zf);
    }

    const float* cp = &CMB[((size_t)(wi * 16 + h)) << 12];
    const int r0 = w * 16 + lg * 4;
    float p[4][4];
    #pragma unroll
    for (int r = 0; r < 4; ++r) {
      float mx = -3.0e38f;
      #pragma unroll
      for (int q4 = 0; q4 < 4; ++q4) {
        float v = s4[q4][r] + cp[(r0 + r) * 64 + q4 * 16 + cl];
        p[q4][r] = v; mx = fmaxf(mx, v);
      }
      mx = fmaxf(mx, __shfl_xor(mx, 1));
      mx = fmaxf(mx, __shfl_xor(mx, 2));
      mx = fmaxf(mx, __shfl_xor(mx, 4));
      mx = fmaxf(mx, __shfl_xor(mx, 8));
      float sum = 0.f;
      #pragma unroll
      for (int q4 = 0; q4 < 4; ++q4) { float e = __expf(p[q4][r] - mx); p[q4][r] = e; sum += e; }
      sum += __shfl_xor(sum, 1); sum += __shfl_xor(sum, 2);
      sum += __shfl_xor(sum, 4); sum += __shfl_xor(sum, 8);
      float inv = 1.f / sum;
      #pragma unroll
      for (int q4 = 0; q4 < 4; ++q4) p[q4][r] *= inv;
    }
    __syncthreads();

    #pragma unroll
    for (int r = 0; r < 4; ++r)
      #pragma unroll
      for (int q4 = 0; q4 < 4; ++q4)
        ps[(r0 + r) * 72 + q4 * 16 + cl] = f2bf(p[q4][r]);

    f32x4 o4[2]; o4[0] = zf; o4[1] = zf;
    #pragma unroll
    for (int ks = 0; ks < 2; ++ks) {
      bf16x8 ap = *(const bf16x8*)&ps[(w * 16 + cl) * 72 + ks * 32 + lg * 8];
      #pragma unroll
      for (int n2 = 0; n2 < 2; ++n2) {
        bf16x8 bv = *(const bf16x8*)&vt[(n2 * 16 + cl) * 72 + ks * 32 + lg * 8];
        o4[n2] = mfma16(ap, bv, o4[n2]);
      }
    }
    #pragma unroll
    for (int n2 = 0; n2 < 2; ++n2)
      #pragma unroll
      for (int r = 0; r < 4; ++r)
        QKV[base + (size_t)(w * 16 + lg * 4 + r) * 1536 + h * 32 + n2 * 16 + cl] = f2bf(o4[n2][r]);
    __syncthreads();
  }
}

// ---------------- proj GEMM (round-2): bf16 [131072,512](lda=1536) @ WPB^T + b -> f32 ----

__global__ __launch_bounds__(256, 2) void proj_gemm(
    const u16* __restrict__ A, const u16* __restrict__ WB,
    const float* __restrict__ PB, float* __restrict__ OUT) {
  __shared__ u16 As[128 * 64];
  __shared__ u16 Bs[128 * 64];
  const int tid = threadIdx.x, lane = tid & 63, w = tid >> 6;
  int bid = blockIdx.x;
  int swz = (bid & 7) * 512 + (bid >> 3);
  const int mt = swz >> 2, nt = swz & 3;
  const long m0 = (long)mt * 128, n0 = (long)nt * 128;
  const int wm = w >> 1, wn = w & 1;
  const f32x4 zf = {0.f, 0.f, 0.f, 0.f};

  f32x4 acc[4][4];
  #pragma unroll
  for (int mi = 0; mi < 4; ++mi)
    #pragma unroll
    for (int ni = 0; ni < 4; ++ni) acc[mi][ni] = zf;

  const int fr = lane & 15;
  const int fsw = ((lane >> 4) ^ (lane & 7)) * 8;
  const u16* Ap = &As[(wm * 64 + fr) * 64 + fsw];
  const u16* Bp = &Bs[(wn * 64 + fr) * 64 + fsw];

  for (int t = 0; t < 8; ++t) {
    #pragma unroll
    for (int i = 0; i < 4; ++i) {
      int ch = ((w << 2) + i) * 64 + lane;
      int row = ch >> 3, kc = (ch & 7) ^ (row & 7);
      gl_lds16(&A[(m0 + row) * 1536 + t * 64 + kc * 8], &As[((w << 2) + i) * 512]);
      gl_lds16(&WB[(n0 + row) * 512 + t * 64 + kc * 8], &Bs[((w << 2) + i) * 512]);
    }
    __syncthreads();
    #pragma unroll
    for (int ks = 0; ks < 2; ++ks) {
      bf16x8 af[4], bfr[4];
      #pragma unroll
      for (int mi = 0; mi < 4; ++mi) af[mi] = ldswz(Ap + mi * 1024, ks);
      #pragma unroll
      for (int ni = 0; ni < 4; ++ni) bfr[ni] = ldswz(Bp + ni * 1024, ks);
      #pragma unroll
      for (int mi = 0; mi < 4; ++mi)
        #pragma unroll
        for (int ni = 0; ni < 4; ++ni)
          acc[mi][ni] = mfma16(af[mi], bfr[ni], acc[mi][ni]);
    }
    __syncthreads();
  }

  #pragma unroll
  for (int ni = 0; ni < 4; ++ni) {
    const long c = n0 + wn * 64 + ni * 16 + fr;
    float bias = PB[c];
    #pragma unroll
    for (int mi = 0; mi < 4; ++mi)
      #pragma unroll
      for (int r = 0; r < 4; ++r) {
        long row = m0 + wm * 64 + mi * 16 + (lane >> 4) * 4 + r;
        OUT[row * 512 + c] = acc[mi][ni][r] + bias;
      }
  }
}

// ---------------- launch ----------------

extern "C" void kernel_launch(void* const* d_in, const int* in_sizes, int n_in,
                              void* d_out, int out_size, void* d_ws, size_t ws_size,
                              hipStream_t stream) {
  const float* X    = (const float*)d_in[0];
  const float* MASK = (const float*)d_in[1];
  const float* QW   = (const float*)d_in[2];
  const float* QB   = (const float*)d_in[3];
  const float* VB   = (const float*)d_in[4];
  const float* LS   = (const float*)d_in[5];
  const float* CW1  = (const float*)d_in[6];
  const float* CB1  = (const float*)d_in[7];
  const float* CW2  = (const float*)d_in[8];
  const float* PW   = (const float*)d_in[9];
  const float* PB   = (const float*)d_in[10];
  const float* CT   = (const float*)d_in[11];
  const int*   RPI  = (const int*)d_in[12];
  float* OUT = (float*)d_out;

  char* ws = (char*)d_ws;
  const bool big = ws_size >= 543178752ull;
  u16* QKV = (u16*)ws;                                    // 402,653,184 B
  u16* XB  = (u16*)(ws + 402653184ull);                   // 134,217,728 B (big only)
  size_t off = big ? 536870912ull : 402653184ull;
  float* CMB = (float*)(ws + off);  off += 4194304ull;    // 4 MB
  float* SIG = (float*)(ws + off);  off += 16384ull;
  u16*   WQB = (u16*)(ws + off);    off += 1572864ull;
  u16*   WPB = (u16*)(ws + off);

  conv_w_kernel<<<1024, 256, 0, stream>>>(QW, PW, WQB, WPB);
  sig16_kernel<<<225, 256, 0, stream>>>(CT, CW1, CB1, CW2, SIG);
  cmb_kernel<<<256, 256, 0, stream>>>(SIG, MASK, RPI, CMB);
  if (big) {
    xconv_kernel<<<32768, 256, 0, stream>>>(X, XB);
    qkv_gemm8<<<3072, 512, 0, stream>>>(XB, WQB, QB, VB, QKV);
  } else {
    qkv_gemm_rs<<<12288, 256, 0, stream>>>(X, WQB, QB, VB, QKV);
  }
  attn_kernel<<<2048, 256, 0, stream>>>(QKV, CMB, LS);
  proj_gemm<<<4096, 256, 0, stream>>>(QKV, WPB, PB, OUT);
}

// Round 5
// 777.436 us; speedup vs baseline: 1.1727x; 1.0601x over previous
//
#include <hip/hip_runtime.h>
#include <stdint.h>
#include <stddef.h>

// SwinV2-B stage-3 window attention, MI355X bf16-MFMA pipeline.
// Round 5: zigzag-quadrant register-reuse in the 8-wave 256x256 pipeline
// (each LDS fragment read exactly once per K-tile: 24 ds_read_b128/wave/K-tile),
// and proj ported to the same template.
// Big ws layout (ws_size >= 543,178,752 B):
//   [0)            QKV bf16 [131072][1536]
//   [402653184)    XB  bf16 [131072][512]
//   [536870912)    CMB f32 [16w][16h][64][64]
//   [541065216)    SIG f32 [225][16] (pad 16K)
//   [541081600)    WQB bf16 [1536][512]
//   [542654464)    WPB bf16 [512][512]

typedef __attribute__((ext_vector_type(8))) short bf16x8;
typedef __attribute__((ext_vector_type(4))) float f32x4;
typedef __attribute__((ext_vector_type(4))) unsigned short us4;
typedef __attribute__((ext_vector_type(8))) unsigned short us8;
typedef unsigned short u16;
typedef unsigned int u32;

#define FENCE() asm volatile("" ::: "memory")
#define WAITV4() asm volatile("s_waitcnt vmcnt(4)" ::: "memory")
#define WAITV0() asm volatile("s_waitcnt vmcnt(0)" ::: "memory")
#define WAITL0() asm volatile("s_waitcnt lgkmcnt(0)" ::: "memory")

__device__ __forceinline__ u16 f2bf(float f) {
  union { __bf16 b; u16 u; } cv;
  cv.b = (__bf16)f;            // hardware RNE convert on gfx950
  return cv.u;
}
__device__ __forceinline__ float bf2f(u16 s) {
  return __uint_as_float(((u32)s) << 16);
}
__device__ __forceinline__ void gl_lds16(const void* g, void* l) {
  __builtin_amdgcn_global_load_lds(
      (const __attribute__((address_space(1))) u32*)g,
      (__attribute__((address_space(3))) u32*)l, 16, 0, 0);
}
__device__ __forceinline__ f32x4 mfma16(bf16x8 a, bf16x8 b, f32x4 c) {
  return __builtin_amdgcn_mfma_f32_16x16x32_bf16(a, b, c, 0, 0, 0);
}
__device__ __forceinline__ bf16x8 ldswz(const u16* p, int ks) {
  return *(const bf16x8*)((const u16*)((uintptr_t)p ^ (uintptr_t)(ks << 6)));
}

// ---------------- prep kernels ----------------

__global__ void conv_w_kernel(const float* __restrict__ QW, const float* __restrict__ PW,
                              u16* __restrict__ WQB, u16* __restrict__ WPB) {
  int idx = blockIdx.x * 256 + threadIdx.x;   // 262144 float4 chunks total
  const int NQ = 1536 * 512 / 4;              // 196608
  float4 v; u16* dst;
  if (idx < NQ) { v = ((const float4*)QW)[idx]; dst = WQB + (size_t)idx * 4; }
  else { int k = idx - NQ; v = ((const float4*)PW)[k]; dst = WPB + (size_t)k * 4; }
  us4 u; u.x = f2bf(v.x); u.y = f2bf(v.y); u.z = f2bf(v.z); u.w = f2bf(v.w);
  *(us4*)dst = u;
}

__global__ void xconv_kernel(const float* __restrict__ X, u16* __restrict__ XB) {
  size_t idx = (size_t)blockIdx.x * 256 + threadIdx.x;   // 8,388,608 threads, 8 f32 each
  float4 a = ((const float4*)X)[idx * 2];
  float4 b = ((const float4*)X)[idx * 2 + 1];
  us8 o;
  o[0] = f2bf(a.x); o[1] = f2bf(a.y); o[2] = f2bf(a.z); o[3] = f2bf(a.w);
  o[4] = f2bf(b.x); o[5] = f2bf(b.y); o[6] = f2bf(b.z); o[7] = f2bf(b.w);
  *(us8*)&XB[idx * 8] = o;
}

__global__ void sig16_kernel(const float* __restrict__ CT, const float* __restrict__ W1,
                             const float* __restrict__ B1, const float* __restrict__ W2,
                             float* __restrict__ SIG) {
  int i = blockIdx.x;            // 0..224
  int tid = threadIdx.x;         // 256
  float c0 = CT[i * 2 + 0], c1 = CT[i * 2 + 1];
  float a[16];
  #pragma unroll
  for (int hh = 0; hh < 16; ++hh) a[hh] = 0.f;
  #pragma unroll
  for (int jj = 0; jj < 2; ++jj) {
    int j = tid + jj * 256;
    float h = fmaxf(c0 * W1[j * 2 + 0] + c1 * W1[j * 2 + 1] + B1[j], 0.f);
    #pragma unroll
    for (int hh = 0; hh < 16; ++hh) a[hh] += h * W2[hh * 512 + j];
  }
  __shared__ float red[4][16];
  #pragma unroll
  for (int hh = 0; hh < 16; ++hh) {
    float v = a[hh];
    for (int m = 1; m < 64; m <<= 1) v += __shfl_xor(v, m);
    if ((tid & 63) == 0) red[tid >> 6][hh] = v;
  }
  __syncthreads();
  if (tid < 16) {
    float v = red[0][tid] + red[1][tid] + red[2][tid] + red[3][tid];
    SIG[i * 16 + tid] = 16.f / (1.f + __expf(-v));
  }
}

__global__ void cmb_kernel(const float* __restrict__ SIG, const float* __restrict__ MASK,
                           const int* __restrict__ RPI, float* __restrict__ CMB) {
  int b = blockIdx.x;            // (w,h) = 256 blocks
  int w = b >> 4, h = b & 15;
  int tid = threadIdx.x;
  const float* mrow = &MASK[(size_t)w * 4096];
  float* crow = &CMB[(size_t)b * 4096];
  #pragma unroll
  for (int it = 0; it < 16; ++it) {
    int nm = it * 256 + tid;
    crow[nm] = SIG[RPI[nm] * 16 + h] + mrow[nm];
  }
}

// ============ shared 256x256/8-wave zigzag pipeline (macro body) ============
// Phases per K-tile t: P0 loads A-quad0+B-quad0, mfma(0,0); P1 loads B-quad1,
// mfma(0,1); P2 loads A-quad1, mfma(1,1); P3 loads nothing, mfma(1,0).
// Stages: P0->B1(t+1), P1->A1(t+1), P2->A0(t+2), P3->B0(t+2)+vmcnt(4).

#define MFMA_QUAD(MB, NB, B0, B1)                                          \
  FENCE(); __builtin_amdgcn_s_barrier(); FENCE();                          \
  WAITL0(); __builtin_amdgcn_sched_barrier(0);                             \
  __builtin_amdgcn_s_setprio(1);                                           \
  _Pragma("unroll")                                                        \
  for (int m = 0; m < 4; ++m)                                              \
    _Pragma("unroll")                                                      \
    for (int n = 0; n < 2; ++n) {                                          \
      acc[(MB) + m][(NB) + n] = mfma16(af0[m], B0[n], acc[(MB) + m][(NB) + n]); \
      acc[(MB) + m][(NB) + n] = mfma16(af1[m], B1[n], acc[(MB) + m][(NB) + n]); \
    }                                                                      \
  __builtin_amdgcn_s_setprio(0);                                           \
  FENCE(); __builtin_amdgcn_s_barrier(); FENCE();

#define GEMM8_KLOOP()                                                      \
  for (int t = 0; t < 8; ++t) {                                            \
    const int buf = (t & 1) * 32768;                                       \
    /* P0 */                                                               \
    _Pragma("unroll")                                                      \
    for (int m = 0; m < 4; ++m) {                                          \
      const u16* pA = &S[buf + (wm * 64 + m * 16 + fr) * 64 + fsw];        \
      af0[m] = ldswz(pA, 0); af1[m] = ldswz(pA, 1);                        \
    }                                                                      \
    _Pragma("unroll")                                                      \
    for (int n = 0; n < 2; ++n) {                                          \
      const u16* pB = &S[buf + 16384 + (wn * 32 + n * 16 + fr) * 64 + fsw];\
      b00[n] = ldswz(pB, 0); b01[n] = ldswz(pB, 1);                        \
    }                                                                      \
    if (t < 7) stageB(t + 1, 1);                                           \
    MFMA_QUAD(0, 0, b00, b01)                                              \
    /* P1 */                                                               \
    _Pragma("unroll")                                                      \
    for (int n = 0; n < 2; ++n) {                                          \
      const u16* pB = &S[buf + 16384 + (128 + wn * 32 + n * 16 + fr) * 64 + fsw]; \
      b10[n] = ldswz(pB, 0); b11[n] = ldswz(pB, 1);                        \
    }                                                                      \
    if (t < 7) stageA(t + 1, 1);                                           \
    MFMA_QUAD(0, 2, b10, b11)                                              \
    /* P2 */                                                               \
    _Pragma("unroll")                                                      \
    for (int m = 0; m < 4; ++m) {                                          \
      const u16* pA = &S[buf + (128 + wm * 64 + m * 16 + fr) * 64 + fsw];  \
      af0[m] = ldswz(pA, 0); af1[m] = ldswz(pA, 1);                        \
    }                                                                      \
    if (t < 6) stageA(t + 2, 0);                                           \
    MFMA_QUAD(4, 2, b10, b11)                                              \
    /* P3 */                                                               \
    if (t < 6) { stageB(t + 2, 0); WAITV4(); }                             \
    else if (t == 6) { WAITV0(); }                                         \
    MFMA_QUAD(4, 0, b00, b01)                                              \
  }

// ---------------- qkv GEMM: XB bf16 [131072,512] @ WQB^T -> bf16 [131072,1536] ----

__global__ __launch_bounds__(512, 1) void qkv_gemm8(
    const u16* __restrict__ XB, const u16* __restrict__ WB,
    const float* __restrict__ QB, const float* __restrict__ VB,
    u16* __restrict__ QKV) {
  __shared__ u16 S[65536];  // [buf:2][ A[256][64] | B[256][64] ]  131072 B
  const int tid = threadIdx.x, lane = tid & 63, w = tid >> 6;
  int bid = blockIdx.x;                           // 3072 = 512m x 6n
  int swz = (bid & 7) * 384 + (bid >> 3);         // bijective XCD swizzle
  const int mt = swz / 6, nt = swz - mt * 6;
  const long m0 = (long)mt * 256, n0 = (long)nt * 256;
  const int wm = w >> 2, wn = w & 3;
  const int fr = lane & 15, lg = lane >> 4;
  const int fsw = (lg ^ (lane & 7)) << 3;
  const f32x4 zf = {0.f, 0.f, 0.f, 0.f};

  f32x4 acc[8][4];
  #pragma unroll
  for (int mi = 0; mi < 8; ++mi)
    #pragma unroll
    for (int ni = 0; ni < 4; ++ni) acc[mi][ni] = zf;

  auto stageA = [&](int kt, int h) {
    int dst = (kt & 1) * 32768 + h * 8192;
    #pragma unroll
    for (int i = 0; i < 2; ++i) {
      int ch = i * 512 + tid;
      int row = ch >> 3, kcs = (ch & 7) ^ (row & 7);
      gl_lds16(&XB[(size_t)(m0 + h * 128 + row) * 512 + kt * 64 + kcs * 8],
               &S[dst + (i * 512 + w * 64) * 8]);
    }
  };
  auto stageB = [&](int kt, int h) {
    int dst = (kt & 1) * 32768 + 16384 + h * 8192;
    #pragma unroll
    for (int i = 0; i < 2; ++i) {
      int ch = i * 512 + tid;
      int row = ch >> 3, kcs = (ch & 7) ^ (row & 7);
      gl_lds16(&WB[(size_t)(n0 + h * 128 + row) * 512 + kt * 64 + kcs * 8],
               &S[dst + (i * 512 + w * 64) * 8]);
    }
  };

  bf16x8 af0[4], af1[4], b00[2], b01[2], b10[2], b11[2];

  stageA(0, 0); stageB(0, 0); stageB(0, 1); stageA(0, 1);
  stageA(1, 0); stageB(1, 0);
  WAITV4();
  FENCE(); __builtin_amdgcn_s_barrier(); FENCE();

  GEMM8_KLOOP()

  #pragma unroll
  for (int ni = 0; ni < 4; ++ni) {
    const long c = n0 + (ni >> 1) * 128 + wn * 32 + (ni & 1) * 16 + fr;
    float bias = (c < 512) ? QB[c] : (c < 1024 ? 0.f : VB[c - 1024]);
    #pragma unroll
    for (int mi = 0; mi < 8; ++mi)
      #pragma unroll
      for (int r = 0; r < 4; ++r) {
        long row = m0 + (mi >> 2) * 128 + wm * 64 + (mi & 3) * 16 + lg * 4 + r;
        QKV[row * 1536 + c] = f2bf(acc[mi][ni][r] + bias);
      }
  }
}

// ---------------- proj GEMM: QKV q-cols bf16 [131072,512](lda=1536) @ WPB^T + b -> f32 ----

__global__ __launch_bounds__(512, 1) void proj_gemm8(
    const u16* __restrict__ A, const u16* __restrict__ WB,
    const float* __restrict__ PB, float* __restrict__ OUT) {
  __shared__ u16 S[65536];
  const int tid = threadIdx.x, lane = tid & 63, w = tid >> 6;
  int bid = blockIdx.x;                           // 1024 = 512m x 2n
  int swz = (bid & 7) * 128 + (bid >> 3);
  const int mt = swz >> 1, nt = swz & 1;
  const long m0 = (long)mt * 256, n0 = (long)nt * 256;
  const int wm = w >> 2, wn = w & 3;
  const int fr = lane & 15, lg = lane >> 4;
  const int fsw = (lg ^ (lane & 7)) << 3;
  const f32x4 zf = {0.f, 0.f, 0.f, 0.f};

  f32x4 acc[8][4];
  #pragma unroll
  for (int mi = 0; mi < 8; ++mi)
    #pragma unroll
    for (int ni = 0; ni < 4; ++ni) acc[mi][ni] = zf;

  auto stageA = [&](int kt, int h) {
    int dst = (kt & 1) * 32768 + h * 8192;
    #pragma unroll
    for (int i = 0; i < 2; ++i) {
      int ch = i * 512 + tid;
      int row = ch >> 3, kcs = (ch & 7) ^ (row & 7);
      gl_lds16(&A[(size_t)(m0 + h * 128 + row) * 1536 + kt * 64 + kcs * 8],
               &S[dst + (i * 512 + w * 64) * 8]);
    }
  };
  auto stageB = [&](int kt, int h) {
    int dst = (kt & 1) * 32768 + 16384 + h * 8192;
    #pragma unroll
    for (int i = 0; i < 2; ++i) {
      int ch = i * 512 + tid;
      int row = ch >> 3, kcs = (ch & 7) ^ (row & 7);
      gl_lds16(&WB[(size_t)(n0 + h * 128 + row) * 512 + kt * 64 + kcs * 8],
               &S[dst + (i * 512 + w * 64) * 8]);
    }
  };

  bf16x8 af0[4], af1[4], b00[2], b01[2], b10[2], b11[2];

  stageA(0, 0); stageB(0, 0); stageB(0, 1); stageA(0, 1);
  stageA(1, 0); stageB(1, 0);
  WAITV4();
  FENCE(); __builtin_amdgcn_s_barrier(); FENCE();

  GEMM8_KLOOP()

  #pragma unroll
  for (int ni = 0; ni < 4; ++ni) {
    const long c = n0 + (ni >> 1) * 128 + wn * 32 + (ni & 1) * 16 + fr;
    float bias = PB[c];
    #pragma unroll
    for (int mi = 0; mi < 8; ++mi)
      #pragma unroll
      for (int r = 0; r < 4; ++r) {
        long row = m0 + (mi >> 2) * 128 + wm * 64 + (mi & 3) * 16 + lg * 4 + r;
        OUT[row * 512 + c] = acc[mi][ni][r] + bias;
      }
  }
}

// ---------------- qkv GEMM fallback (small ws): reg-staged A, 128x128 ----------------

__global__ __launch_bounds__(256, 2) void qkv_gemm_rs(
    const float* __restrict__ X, const u16* __restrict__ WB,
    const float* __restrict__ QB, const float* __restrict__ VB,
    u16* __restrict__ QKV) {
  __shared__ u16 As[128 * 64];
  __shared__ u16 Bs[128 * 64];
  const int tid = threadIdx.x, lane = tid & 63, w = tid >> 6;
  int bid = blockIdx.x;
  int swz = (bid & 7) * 1536 + (bid >> 3);
  const int mt = swz / 12, nt = swz - mt * 12;
  const long m0 = (long)mt * 128, n0 = (long)nt * 128;
  const int wm = w >> 1, wn = w & 1;
  const f32x4 zf = {0.f, 0.f, 0.f, 0.f};

  f32x4 acc[4][4];
  #pragma unroll
  for (int mi = 0; mi < 4; ++mi)
    #pragma unroll
    for (int ni = 0; ni < 4; ++ni) acc[mi][ni] = zf;

  const int fr = lane & 15;
  const int fsw = ((lane >> 4) ^ (lane & 7)) * 8;
  const u16* Ap = &As[(wm * 64 + fr) * 64 + fsw];
  const u16* Bp = &Bs[(wn * 64 + fr) * 64 + fsw];

  for (int t = 0; t < 8; ++t) {
    float4 av[8];
    #pragma unroll
    for (int i = 0; i < 8; ++i) {
      int ch = tid + (i << 8);
      int row = ch >> 4, kc = ch & 15;
      av[i] = *(const float4*)&X[(m0 + row) * 512 + t * 64 + kc * 4];
    }
    #pragma unroll
    for (int i = 0; i < 4; ++i) {
      int ch = ((w << 2) + i) * 64 + lane;
      int row = ch >> 3, kc = (ch & 7) ^ (row & 7);
      gl_lds16(&WB[(n0 + row) * 512 + t * 64 + kc * 8], &Bs[((w << 2) + i) * 512]);
    }
    #pragma unroll
    for (int i = 0; i < 8; ++i) {
      int ch = tid + (i << 8);
      int row = ch >> 4, kc = ch & 15;
      int kcs = kc ^ ((row & 7) << 1);
      us4 u; u.x = f2bf(av[i].x); u.y = f2bf(av[i].y); u.z = f2bf(av[i].z); u.w = f2bf(av[i].w);
      *(us4*)&As[row * 64 + kcs * 4] = u;
    }
    __syncthreads();
    #pragma unroll
    for (int ks = 0; ks < 2; ++ks) {
      bf16x8 af[4], bfr[4];
      #pragma unroll
      for (int mi = 0; mi < 4; ++mi) af[mi] = ldswz(Ap + mi * 1024, ks);
      #pragma unroll
      for (int ni = 0; ni < 4; ++ni) bfr[ni] = ldswz(Bp + ni * 1024, ks);
      #pragma unroll
      for (int mi = 0; mi < 4; ++mi)
        #pragma unroll
        for (int ni = 0; ni < 4; ++ni)
          acc[mi][ni] = mfma16(af[mi], bfr[ni], acc[mi][ni]);
    }
    __syncthreads();
  }

  #pragma unroll
  for (int ni = 0; ni < 4; ++ni) {
    const long c = n0 + wn * 64 + ni * 16 + (lane & 15);
    float bias = (c < 512) ? QB[c] : (c < 1024 ? 0.f : VB[c - 1024]);
    #pragma unroll
    for (int mi = 0; mi < 4; ++mi)
      #pragma unroll
      for (int r = 0; r < 4; ++r) {
        long row = m0 + wm * 64 + mi * 16 + (lane >> 4) * 4 + r;
        QKV[row * 1536 + c] = f2bf(acc[mi][ni][r] + bias);
      }
  }
}

// ---------------- attention: 1 block per window, 4 waves coop per head ----------------

__global__ __launch_bounds__(256, 4) void attn_kernel(
    u16* __restrict__ QKV, const float* __restrict__ CMB, const float* __restrict__ LS) {
  __shared__ u16 sm[7424];       // 14848 B
  u16* qs = sm;                  // [64][40] (aliased by ps)
  u16* ksm = sm + 2560;          // [64][40] (aliased by ps)
  u16* ps = sm;                  // [64][72]
  u16* vt = sm + 5120;           // [32][72] (v transposed: [d][k])
  const int tid = threadIdx.x, lane = tid & 63, w = tid >> 6;
  const int b = blockIdx.x, wi = b & 15;
  const size_t base = (size_t)b * 64 * 1536;
  const int cl = lane & 15, lg = lane >> 4;
  const int srow = tid >> 2, sck = tid & 3;
  const int vd = tid & 31, vkb = tid >> 5;
  const f32x4 zf = {0.f, 0.f, 0.f, 0.f};

  for (int h = 0; h < 16; ++h) {
    const float scale = __expf(fminf(LS[h], 4.6051702f));
    {
      us8 qv = *(const us8*)&QKV[base + (size_t)srow * 1536 + h * 32 + sck * 8];
      float qf[8]; float ss = 0.f;
      #pragma unroll
      for (int j = 0; j < 8; ++j) { qf[j] = bf2f(qv[j]); ss += qf[j] * qf[j]; }
      ss += __shfl_xor(ss, 1); ss += __shfl_xor(ss, 2);
      float rn = scale / fmaxf(sqrtf(ss), 1e-12f);
      us8 qo;
      #pragma unroll
      for (int j = 0; j < 8; ++j) qo[j] = f2bf(qf[j] * rn);
      *(us8*)&qs[srow * 40 + sck * 8] = qo;
    }
    {
      us8 kv = *(const us8*)&QKV[base + (size_t)srow * 1536 + 512 + h * 32 + sck * 8];
      float kf[8]; float ss = 0.f;
      #pragma unroll
      for (int j = 0; j < 8; ++j) { kf[j] = bf2f(kv[j]); ss += kf[j] * kf[j]; }
      ss += __shfl_xor(ss, 1); ss += __shfl_xor(ss, 2);
      float rn = 1.f / fmaxf(sqrtf(ss), 1e-12f);
      us8 ko;
      #pragma unroll
      for (int j = 0; j < 8; ++j) ko[j] = f2bf(kf[j] * rn);
      *(us8*)&ksm[srow * 40 + sck * 8] = ko;
    }
    {
      us8 vo;
      #pragma unroll
      for (int e = 0; e < 8; ++e)
        vo[e] = QKV[base + (size_t)(vkb * 8 + e) * 1536 + 1024 + h * 32 + vd];
      *(us8*)&vt[vd * 72 + vkb * 8] = vo;
    }
    __syncthreads();

    bf16x8 aq = *(const bf16x8*)&qs[(w * 16 + cl) * 40 + lg * 8];
    f32x4 s4[4];
    #pragma unroll
    for (int nt = 0; nt < 4; ++nt) {
      bf16x8 bk = *(const bf16x8*)&ksm[(nt * 16 + cl) * 40 + lg * 8];
      s4[nt] = mfma16(aq, bk, zf);
    }

    const float* cp = &CMB[((size_t)(wi * 16 + h)) << 12];
    const int r0 = w * 16 + lg * 4;
    float p[4][4];
    #pragma unroll
    for (int r = 0; r < 4; ++r) {
      float mx = -3.0e38f;
      #pragma unroll
      for (int q4 = 0; q4 < 4; ++q4) {
        float v = s4[q4][r] + cp[(r0 + r) * 64 + q4 * 16 + cl];
        p[q4][r] = v; mx = fmaxf(mx, v);
      }
      mx = fmaxf(mx, __shfl_xor(mx, 1));
      mx = fmaxf(mx, __shfl_xor(mx, 2));
      mx = fmaxf(mx, __shfl_xor(mx, 4));
      mx = fmaxf(mx, __shfl_xor(mx, 8));
      float sum = 0.f;
      #pragma unroll
      for (int q4 = 0; q4 < 4; ++q4) { float e = __expf(p[q4][r] - mx); p[q4][r] = e; sum += e; }
      sum += __shfl_xor(sum, 1); sum += __shfl_xor(sum, 2);
      sum += __shfl_xor(sum, 4); sum += __shfl_xor(sum, 8);
      float inv = 1.f / sum;
      #pragma unroll
      for (int q4 = 0; q4 < 4; ++q4) p[q4][r] *= inv;
    }
    __syncthreads();

    #pragma unroll
    for (int r = 0; r < 4; ++r)
      #pragma unroll
      for (int q4 = 0; q4 < 4; ++q4)
        ps[(r0 + r) * 72 + q4 * 16 + cl] = f2bf(p[q4][r]);

    f32x4 o4[2]; o4[0] = zf; o4[1] = zf;
    #pragma unroll
    for (int ks = 0; ks < 2; ++ks) {
      bf16x8 ap = *(const bf16x8*)&ps[(w * 16 + cl) * 72 + ks * 32 + lg * 8];
      #pragma unroll
      for (int n2 = 0; n2 < 2; ++n2) {
        bf16x8 bv = *(const bf16x8*)&vt[(n2 * 16 + cl) * 72 + ks * 32 + lg * 8];
        o4[n2] = mfma16(ap, bv, o4[n2]);
      }
    }
    #pragma unroll
    for (int n2 = 0; n2 < 2; ++n2)
      #pragma unroll
      for (int r = 0; r < 4; ++r)
        QKV[base + (size_t)(w * 16 + lg * 4 + r) * 1536 + h * 32 + n2 * 16 + cl] = f2bf(o4[n2][r]);
    __syncthreads();
  }
}

// ---------------- launch ----------------

extern "C" void kernel_launch(void* const* d_in, const int* in_sizes, int n_in,
                              void* d_out, int out_size, void* d_ws, size_t ws_size,
                              hipStream_t stream) {
  const float* X    = (const float*)d_in[0];
  const float* MASK = (const float*)d_in[1];
  const float* QW   = (const float*)d_in[2];
  const float* QB   = (const float*)d_in[3];
  const float* VB   = (const float*)d_in[4];
  const float* LS   = (const float*)d_in[5];
  const float* CW1  = (const float*)d_in[6];
  const float* CB1  = (const float*)d_in[7];
  const float* CW2  = (const float*)d_in[8];
  const float* PW   = (const float*)d_in[9];
  const float* PB   = (const float*)d_in[10];
  const float* CT   = (const float*)d_in[11];
  const int*   RPI  = (const int*)d_in[12];
  float* OUT = (float*)d_out;

  char* ws = (char*)d_ws;
  const bool big = ws_size >= 543178752ull;
  u16* QKV = (u16*)ws;                                    // 402,653,184 B
  u16* XB  = (u16*)(ws + 402653184ull);                   // 134,217,728 B (big only)
  size_t off = big ? 536870912ull : 402653184ull;
  float* CMB = (float*)(ws + off);  off += 4194304ull;    // 4 MB
  float* SIG = (float*)(ws + off);  off += 16384ull;
  u16*   WQB = (u16*)(ws + off);    off += 1572864ull;
  u16*   WPB = (u16*)(ws + off);

  conv_w_kernel<<<1024, 256, 0, stream>>>(QW, PW, WQB, WPB);
  sig16_kernel<<<225, 256, 0, stream>>>(CT, CW1, CB1, CW2, SIG);
  cmb_kernel<<<256, 256, 0, stream>>>(SIG, MASK, RPI, CMB);
  if (big) {
    xconv_kernel<<<32768, 256, 0, stream>>>(X, XB);
    qkv_gemm8<<<3072, 512, 0, stream>>>(XB, WQB, QB, VB, QKV);
  } else {
    qkv_gemm_rs<<<12288, 256, 0, stream>>>(X, WQB, QB, VB, QKV);
  }
  attn_kernel<<<2048, 256, 0, stream>>>(QKV, CMB, LS);
  proj_gemm8<<<1024, 512, 0, stream>>>(QKV, WPB, PB, OUT);
}